// Round 8
// baseline (663.683 us; speedup 1.0000x reference)
//
#include <hip/hip_runtime.h>
#include <hip/hip_cooperative_groups.h>
#include <math.h>

namespace cg = cooperative_groups;

#define Hh 96
#define Ww 96
#define NPIX 9216
#define RAD 15
#define TAPS 31
#define NCH 144            // chunks of 64 sorted pixels; also grid size
#define GB 144
#define TPB 256
#define NBIN 4096
#define EPSV 1e-20f
#define LOG2E 1.4426950408889634f
#define CUT2 60.0f         // boxdist_h^2 > 60 => k < 2^-43 => safe to skip

// ---- ws layout (4-byte units), ~566 KB, fully rebuilt every call ----
#define OFF_F    0                 // 8*NPIX feat_sorted: h0..h4, a, q, pad
#define OFF_Q    73728             // NPIX   q, ORIGINAL order
#define OFF_CBI  82944             // NPIX   bilateral colsum, SORTED order
#define OFF_BV   92160             // NPIX   bilateral q-filter, SORTED order
#define OFF_ROWW 101376            // 96
#define OFF_WTAB 101472            // 32
#define OFF_BBOX 101504            // NCH*12
// int regions
#define OFF_HIST 103232            // 4096
#define OFF_BASE 107328            // 4096
#define OFF_INV  111424            // NPIX  orig n -> sorted pos
#define OFF_CNT  120640            // NCH
#define OFF_LIST 120784            // NCH*NCH survivor lists

__device__ __forceinline__ int color_key(float r, float g, float b){
  int rq = min(15, (int)r >> 4);
  int gq = min(15, (int)g >> 4);
  int bq = min(15, (int)b >> 4);
  int key = 0;
  #pragma unroll
  for (int k=0;k<4;k++){
    key |= ((rq>>k)&1) << (3*k+2);
    key |= ((gq>>k)&1) << (3*k+1);
    key |= ((bq>>k)&1) << (3*k);
  }
  return key;
}

__global__ __launch_bounds__(TPB) void mega_kernel(const float* __restrict__ image,
                                                   const float* __restrict__ logits,
                                                   const float* __restrict__ Wsp,
                                                   const float* __restrict__ Wbi,
                                                   const float* __restrict__ Cm,
                                                   float* __restrict__ out,
                                                   float* __restrict__ ws){
  cg::grid_group grid = cg::this_grid();
  const int b = blockIdx.x, t = threadIdx.x;
  const int lane = t & 63, wid = t >> 6;
  int* W = (int*)ws;

  __shared__ float tq[46][48];
  __shared__ float tr[46][17];
  __shared__ float wt[TAPS];
  __shared__ float pB[4][64];
  __shared__ float pC[4][64];
  __shared__ int   scn[256];

  // ---- S0: zero hist + spatial tables ----
  {
    int gid = b*TPB + t;
    if (gid < NBIN) W[OFF_HIST + gid] = 0;
    if (b == 16 && t < Hh){
      float s = 0.f;
      for (int yy=0; yy<Hh; ++yy){ float d=(float)(yy-t); s += expf(-d*d*(1.0f/18.0f)); }
      ws[OFF_ROWW + t] = s;                 // full (untruncated) 1-D colsum
    }
    if (b == 17 && t < TAPS){
      int d = t - RAD;
      ws[OFF_WTAB + t] = expf(-(float)(d*d)*(1.0f/18.0f));
    }
  }
  grid.sync();

  // ---- S1: color histogram ----
  {
    int n = b*TPB + t;
    if (n < NPIX){
      int key = color_key(image[n], image[NPIX+n], image[2*NPIX+n]);
      atomicAdd(W + OFF_HIST + key, 1);
    }
  }
  grid.sync();

  // ---- S2: exclusive scan (block 0) ----
  if (b == 0){
    int loc[16]; int s = 0;
    #pragma unroll
    for (int i=0;i<16;i++){ loc[i]=s; s += W[OFF_HIST + t*16+i]; }
    scn[t] = s; __syncthreads();
    for (int off=1; off<256; off<<=1){
      int v = (t>=off) ? scn[t-off] : 0;
      __syncthreads(); scn[t] += v; __syncthreads();
    }
    int base = (t==0)?0:scn[t-1];
    #pragma unroll
    for (int i=0;i<16;i++) W[OFF_BASE + t*16+i] = base + loc[i];
  }
  grid.sync();

  // ---- S3: scatter + feature build + initial softmax q ----
  {
    int n = b*TPB + t;
    if (n < NPIX){
      float r=image[n], g=image[NPIX+n], bl=image[2*NPIX+n];
      int key = color_key(r,g,bl);
      int pos = atomicAdd(W + OFF_BASE + key, 1);
      W[OFF_INV + n] = pos;
      int y=n/Ww, x=n%Ww;
      const float c=0.7213475205f;    // 0.5/ln2
      const float sc=1.2011224088f;   // sqrt(2c)
      float f0=(float)y*(1.f/160.f), f1=(float)x*(1.f/160.f);
      float f2=r*(1.f/3.f), f3=g*(1.f/3.f), f4=bl*(1.f/3.f);
      float a=c*(f0*f0+f1*f1+f2*f2+f3*f3+f4*f4);
      float q = 1.f/(1.f + __builtin_amdgcn_exp2f((logits[NPIX+n]-logits[n])*LOG2E));
      float* F = ws + OFF_F + (size_t)pos*8;
      F[0]=sc*f0; F[1]=sc*f1; F[2]=sc*f2; F[3]=sc*f3; F[4]=sc*f4;
      F[5]=a; F[6]=q; F[7]=0.f;
      ws[OFF_Q + n] = q;
    }
  }
  grid.sync();

  // ---- S4: per-chunk 5-D bbox (wave 0 of each block; block = chunk) ----
  if (wid == 0){
    const float* F = ws + OFF_F + ((size_t)b*64 + lane)*8;
    float4 A = *(const float4*)F;
    float4 B4 = *(const float4*)(F+4);
    float mn[5]={A.x,A.y,A.z,A.w,B4.x}, mx[5]={A.x,A.y,A.z,A.w,B4.x};
    #pragma unroll
    for (int m=32; m; m>>=1){
      #pragma unroll
      for (int d=0;d<5;d++){
        mn[d]=fminf(mn[d], __shfl_xor(mn[d], m));
        mx[d]=fmaxf(mx[d], __shfl_xor(mx[d], m));
      }
    }
    if (lane == 0){
      float* bb = ws + OFF_BBOX + b*12;
      #pragma unroll
      for (int d=0;d<5;d++){ bb[d]=mn[d]; bb[5+d]=mx[d]; }
    }
  }
  grid.sync();

  // ---- S5: cull -> survivor list for this block's j-group ----
  if (wid == 0){
    const float* wb = ws + OFF_BBOX + b*12;
    float wmn[5], wmx[5];
    #pragma unroll
    for (int d=0;d<5;d++){ wmn[d]=wb[d]; wmx[d]=wb[5+d]; }
    int* list = W + OFF_LIST + b*NCH;
    int base = 0;
    #pragma unroll
    for (int r2=0;r2<3;r2++){
      int c2 = lane + 64*r2;
      bool sv = false;
      if (c2 < NCH){
        const float* cb = ws + OFF_BBOX + c2*12;
        float s2 = 0.f;
        #pragma unroll
        for (int d=0;d<5;d++){
          float gap = fmaxf(0.f, fmaxf(cb[d]-wmx[d], wmn[d]-cb[5+d]));
          s2 = fmaf(gap, gap, s2);
        }
        sv = (s2 <= CUT2);
      }
      unsigned long long m = __ballot(sv);
      if (sv){
        int pos = __popcll(m & ((1ull<<lane)-1ull));
        list[base+pos] = c2;
      }
      base += __popcll(m);
    }
    if (lane == 0) W[OFF_CNT + b] = base;
  }
  grid.sync();

  // ===== iteration engine =====
  // bilateral: block = jg; 4 waves split survivor chunks; LDS-reduce.
  #define BILATERAL(COLSUM)                                                    \
  {                                                                            \
    const float* F = ws + OFF_F;                                               \
    int js = b*64 + lane;                                                      \
    float4 A = *(const float4*)(F + (size_t)js*8);                             \
    float4 B4 = *(const float4*)(F + (size_t)js*8 + 4);                        \
    float h0=A.x,h1=A.y,h2=A.z,h3=A.w,h4=B4.x,na=-B4.y;                        \
    int ncnt = W[OFF_CNT + b];                                                 \
    const int* list = W + OFF_LIST + b*NCH;                                    \
    float aB=0.f, aC=0.f;                                                      \
    for (int idx=wid; idx<ncnt; idx+=4){                                       \
      const float* fi = F + (size_t)list[idx]*512;                             \
      _Pragma("unroll 4")                                                      \
      for (int ii=0; ii<64; ii++){                                             \
        float4 w0 = *(const float4*)(fi + ii*8);                               \
        float4 w1 = *(const float4*)(fi + ii*8 + 4);                           \
        float e = na - w1.y;                                                   \
        e = fmaf(h0,w0.x,e); e = fmaf(h1,w0.y,e); e = fmaf(h2,w0.z,e);         \
        e = fmaf(h3,w0.w,e); e = fmaf(h4,w1.x,e);                              \
        float kk = __builtin_amdgcn_exp2f(e);                                  \
        aB = fmaf(kk, w1.z, aB);                                               \
        if (COLSUM) aC += kk;                                                  \
      }                                                                        \
    }                                                                          \
    pB[wid][lane]=aB;                                                          \
    if (COLSUM) pC[wid][lane]=aC;                                              \
    __syncthreads();                                                           \
    if (wid == 0){                                                             \
      ws[OFF_BV+js] = pB[0][lane]+pB[1][lane]+pB[2][lane]+pB[3][lane];         \
      if (COLSUM)                                                              \
        ws[OFF_CBI+js] = pC[0][lane]+pC[1][lane]+pC[2][lane]+pC[3][lane];      \
    }                                                                          \
  }

  // combine: blocks 0..35 = 16x16 spatial tiles; writes out + next-iter q.
  #define COMBINE()                                                            \
  if (b < 36){                                                                 \
    int tx=t&15, ty=t>>4;                                                      \
    int bx=b%6, by=b/6, x0=bx*16, y0=by*16;                                    \
    const float* q0g = ws + OFF_Q;                                             \
    for (int idx=t; idx<46*46; idx+=TPB){                                      \
      int ly=idx/46, lx=idx%46;                                                \
      int gy=y0-RAD+ly, gx=x0-RAD+lx;                                          \
      float v=0.f;                                                             \
      if (gy>=0&&gy<Hh&&gx>=0&&gx<Ww) v=q0g[gy*Ww+gx];                         \
      tq[ly][lx]=v;                                                            \
    }                                                                          \
    if (t<TAPS) wt[t]=ws[OFF_WTAB+t];                                          \
    __syncthreads();                                                           \
    for (int idx=t; idx<46*16; idx+=TPB){                                      \
      int ly=idx>>4, lx=idx&15;                                                \
      float in=0.f;                                                            \
      _Pragma("unroll")                                                        \
      for (int dx=0;dx<TAPS;dx++) in=fmaf(wt[dx],tq[ly][lx+dx],in);            \
      tr[ly][lx]=in;                                                           \
    }                                                                          \
    __syncthreads();                                                           \
    int y=y0+ty, x=x0+tx, j=y*Ww+x;                                            \
    float S=0.f;                                                               \
    _Pragma("unroll")                                                          \
    for (int dy=0;dy<TAPS;dy++) S=fmaf(wt[dy],tr[ty+dy][tx],S);                \
    int js2 = W[OFF_INV + j];                                                  \
    float Bv=ws[OFF_BV+js2], Cb=ws[OFF_CBI+js2];                               \
    float nb=1.f/(Cb+EPSV);                                                    \
    float Csp=ws[OFF_ROWW+y]*ws[OFF_ROWW+x];                                   \
    float nsp=1.f/(Csp+EPSV);                                                  \
    float sp0=S*nsp, sp1=(Csp-S)*nsp;                                          \
    float bi0=Bv*nb, bi1=(Cb-Bv)*nb;                                           \
    float m0=Wsp[0]*sp0+Wsp[1]*sp1+Wbi[0]*bi0+Wbi[1]*bi1;                      \
    float m1=Wsp[2]*sp0+Wsp[3]*sp1+Wbi[2]*bi0+Wbi[3]*bi1;                      \
    float cm0=Cm[0]*m0+Cm[1]*m1, cm1=Cm[2]*m0+Cm[3]*m1;                        \
    float o0=logits[j]-cm0, o1=logits[NPIX+j]-cm1;                             \
    out[j]=o0; out[NPIX+j]=o1;                                                 \
    float qn=1.f/(1.f+__builtin_amdgcn_exp2f((o1-o0)*LOG2E));                  \
    ws[OFF_Q+j]=qn;                                                            \
    ws[OFF_F+(size_t)js2*8+6]=qn;                                              \
  }

  // iter 0: fused colsum + q-filter
  BILATERAL(1)
  grid.sync();
  COMBINE()
  grid.sync();

  for (int it=1; it<5; ++it){
    BILATERAL(0)
    grid.sync();
    COMBINE()
    grid.sync();
  }
}

extern "C" void kernel_launch(void* const* d_in, const int* in_sizes, int n_in,
                              void* d_out, int out_size, void* d_ws, size_t ws_size,
                              hipStream_t stream){
  const float* image  = (const float*)d_in[0];
  const float* logits = (const float*)d_in[1];
  const float* Wsp    = (const float*)d_in[2];
  const float* Wbi    = (const float*)d_in[3];
  const float* Cm     = (const float*)d_in[4];
  float* out = (float*)d_out;
  float* ws  = (float*)d_ws;

  void* args[] = {(void*)&image, (void*)&logits, (void*)&Wsp, (void*)&Wbi,
                  (void*)&Cm, (void*)&out, (void*)&ws};
  hipLaunchCooperativeKernel(mega_kernel, dim3(GB), dim3(TPB), args, 0u, stream);
}

// Round 9
// 375.909 us; speedup vs baseline: 1.7655x; 1.7655x over previous
//
#include <hip/hip_runtime.h>
#include <math.h>

#define Hh 96
#define Ww 96
#define NPIX 9216
#define RAD 15
#define TAPS 31
#define NCH 144            // chunks of 64 sorted pixels
#define NBIN 4096
#define GRIDB 1024         // bilateral blocks (4 waves each -> 4096 waves)
#define EPSV 1e-20f
#define LOG2E 1.4426950408889634f
#define CUT2 60.0f         // boxdist_h^2 > 60 => k < 2^-43 => safe to skip

// ---- ws layout (4-byte units), ~690 KB ----
#define OFF_F    0                 // 8*NPIX feat_sorted: h0..h4, a, q, pad
#define OFF_Q0   73728             // NPIX  q ping (original order)
#define OFF_Q1   82944             // NPIX  q pong
#define OFF_CBI  92160             // NPIX  bilateral colsum, ORIGINAL order
#define OFF_BV   101376            // NPIX  bilateral q-filter, ORIGINAL order
#define OFF_ROWW 110592            // 96
#define OFF_WTAB 110688            // 32
#define OFF_BBOX 110720            // NCH*12 -> 112448
// int regions
#define OFF_INV  112448            // NPIX  orig n -> sorted pos
#define OFF_SRT  121664            // NPIX  sorted pos -> orig n
#define OFF_CNT  130880            // NCH
#define OFF_OFS  131024            // NCH+1
#define OFF_LIST 131169            // NCH*NCH ragged survivor lists
#define OFF_WORK 151905            // NCH*NCH flat worklist (jg<<8|c)

__device__ __forceinline__ int color_key(float r, float g, float b){
  int rq = min(15, (int)r >> 4);
  int gq = min(15, (int)g >> 4);
  int bq = min(15, (int)b >> 4);
  int key = 0;
  #pragma unroll
  for (int k=0;k<4;k++){
    key |= ((rq>>k)&1) << (3*k+2);
    key |= ((gq>>k)&1) << (3*k+1);
    key |= ((bq>>k)&1) << (3*k);
  }
  return key;
}

// Single-block prep: zero BV/CBI, tables, hist, scan, scatter(+q init),
// bbox, cull, pack flat worklist.  Replaces 7 dispatches.
__global__ __launch_bounds__(256) void prep_kernel(const float* __restrict__ image,
                                                   const float* __restrict__ logits,
                                                   float* __restrict__ ws){
  __shared__ int hist[NBIN];
  __shared__ int part[256];
  const int t = threadIdx.x;
  const int lane = t & 63, wid = t >> 6;
  int* W = (int*)ws;

  // zero accumulators + LDS hist, build spatial tables
  for (int i=t; i<NPIX; i+=256){ ws[OFF_BV+i]=0.f; ws[OFF_CBI+i]=0.f; }
  for (int i=t; i<NBIN; i+=256) hist[i]=0;
  if (t < Hh){
    float s = 0.f;
    for (int yy=0; yy<Hh; ++yy){ float d=(float)(yy-t); s += expf(-d*d*(1.0f/18.0f)); }
    ws[OFF_ROWW + t] = s;                 // full 1-D colsum (spatial norm)
  }
  if (t >= 128 && t < 128+TAPS){
    int d = (t-128) - RAD;
    ws[OFF_WTAB + (t-128)] = expf(-(float)(d*d)*(1.0f/18.0f));
  }
  __syncthreads();

  // histogram
  for (int n=t; n<NPIX; n+=256){
    int key = color_key(image[n], image[NPIX+n], image[2*NPIX+n]);
    atomicAdd(&hist[key], 1);
  }
  __syncthreads();

  // exclusive scan of 4096 bins (16 per thread + block scan); write bases back
  {
    int loc[16]; int s = 0;
    #pragma unroll
    for (int i=0;i<16;i++){ loc[i]=s; s += hist[t*16+i]; }
    part[t] = s; __syncthreads();
    for (int off=1; off<256; off<<=1){
      int v = (t>=off) ? part[t-off] : 0;
      __syncthreads(); part[t] += v; __syncthreads();
    }
    int base = (t==0) ? 0 : part[t-1];
    #pragma unroll
    for (int i=0;i<16;i++) hist[t*16+i] = base + loc[i];
  }
  __syncthreads();

  // scatter: sorted feature build + initial softmax q
  for (int n=t; n<NPIX; n+=256){
    float r=image[n], g=image[NPIX+n], bl=image[2*NPIX+n];
    int key = color_key(r,g,bl);
    int pos = atomicAdd(&hist[key], 1);
    W[OFF_INV + n] = pos;
    W[OFF_SRT + pos] = n;
    int y=n/Ww, x=n%Ww;
    const float c=0.7213475205f;    // 0.5/ln2
    const float sc=1.2011224088f;   // sqrt(2c)
    float f0=(float)y*(1.f/160.f), f1=(float)x*(1.f/160.f);
    float f2=r*(1.f/3.f), f3=g*(1.f/3.f), f4=bl*(1.f/3.f);
    float a=c*(f0*f0+f1*f1+f2*f2+f3*f3+f4*f4);
    float q = 1.f/(1.f + __builtin_amdgcn_exp2f((logits[NPIX+n]-logits[n])*LOG2E));
    float* F = ws + OFF_F + (size_t)pos*8;
    F[0]=sc*f0; F[1]=sc*f1; F[2]=sc*f2; F[3]=sc*f3; F[4]=sc*f4;
    F[5]=a; F[6]=q; F[7]=0.f;
    ws[OFF_Q0 + n] = q;
  }
  __syncthreads();

  // per-chunk 5-D bbox (one wave per chunk, strided)
  for (int ch=wid; ch<NCH; ch+=4){
    const float* F = ws + OFF_F + ((size_t)ch*64 + lane)*8;
    float4 A = *(const float4*)F;
    float4 B4 = *(const float4*)(F+4);
    float mn[5]={A.x,A.y,A.z,A.w,B4.x}, mx[5]={A.x,A.y,A.z,A.w,B4.x};
    #pragma unroll
    for (int m=32; m; m>>=1){
      #pragma unroll
      for (int d=0;d<5;d++){
        mn[d]=fminf(mn[d], __shfl_xor(mn[d], m));
        mx[d]=fmaxf(mx[d], __shfl_xor(mx[d], m));
      }
    }
    if (lane == 0){
      float* bb = ws + OFF_BBOX + ch*12;
      #pragma unroll
      for (int d=0;d<5;d++){ bb[d]=mn[d]; bb[5+d]=mx[d]; }
    }
  }
  __syncthreads();

  // cull: survivor chunk lists per j-group (one wave per jg, strided)
  for (int jg=wid; jg<NCH; jg+=4){
    const float* wb = ws + OFF_BBOX + jg*12;
    float wmn[5], wmx[5];
    #pragma unroll
    for (int d=0;d<5;d++){ wmn[d]=wb[d]; wmx[d]=wb[5+d]; }
    int* list = W + OFF_LIST + jg*NCH;
    int base = 0;
    #pragma unroll
    for (int r2=0;r2<3;r2++){
      int c2 = lane + 64*r2;
      bool sv = false;
      if (c2 < NCH){
        const float* cb = ws + OFF_BBOX + c2*12;
        float s2 = 0.f;
        #pragma unroll
        for (int d=0;d<5;d++){
          float gap = fmaxf(0.f, fmaxf(cb[d]-wmx[d], wmn[d]-cb[5+d]));
          s2 = fmaf(gap, gap, s2);
        }
        sv = (s2 <= CUT2);
      }
      unsigned long long m = __ballot(sv);
      if (sv){
        int pos = __popcll(m & ((1ull<<lane)-1ull));
        list[base+pos] = c2;
      }
      base += __popcll(m);
    }
    if (lane == 0) W[OFF_CNT + jg] = base;
  }
  __syncthreads();

  // offsets (serial over 144 — trivial) then pack flat worklist
  if (t == 0){
    int run = 0;
    for (int g=0; g<NCH; ++g){ W[OFF_OFS+g] = run; run += W[OFF_CNT+g]; }
    W[OFF_OFS+NCH] = run;
  }
  __syncthreads();
  for (int g=t; g<NCH; g+=256){
    int base = W[OFF_OFS+g], cnt = W[OFF_CNT+g];
    const int* list = W + OFF_LIST + g*NCH;
    int* work = W + OFF_WORK;
    for (int k=0; k<cnt; ++k) work[base+k] = (g<<8) | list[k];
  }
}

// one WAVE per (jg, chunk) work item; atomic commit into original-order BV/CBI.
// FIRST=1 additionally accumulates the iteration-invariant colsum.
template<int FIRST>
__global__ __launch_bounds__(256) void bil_kernel(float* __restrict__ ws){
  const int lane = threadIdx.x & 63, wid = threadIdx.x >> 6;
  const int* W = (const int*)ws;
  const int T = W[OFF_OFS + NCH];
  const int* work = W + OFF_WORK;
  const int* srt  = W + OFF_SRT;
  const float* F  = ws + OFF_F;
  for (int it = blockIdx.x*4 + wid; it < T; it += GRIDB*4){
    int en = work[it];
    int jg = en >> 8, c = en & 255;
    int js = jg*64 + lane;
    float4 A  = *(const float4*)(F + (size_t)js*8);
    float4 B4 = *(const float4*)(F + (size_t)js*8 + 4);
    float h0=A.x,h1=A.y,h2=A.z,h3=A.w,h4=B4.x,na=-B4.y;
    const float* fi = F + (size_t)c*512;
    float aB=0.f, aC=0.f;
    #pragma unroll 4
    for (int ii=0; ii<64; ii++){
      float4 w0 = *(const float4*)(fi + ii*8);
      float4 w1 = *(const float4*)(fi + ii*8 + 4);
      float e = na - w1.y;
      e=fmaf(h0,w0.x,e); e=fmaf(h1,w0.y,e); e=fmaf(h2,w0.z,e);
      e=fmaf(h3,w0.w,e); e=fmaf(h4,w1.x,e);
      float kk = __builtin_amdgcn_exp2f(e);
      aB = fmaf(kk, w1.z, aB);
      if (FIRST) aC += kk;
    }
    int n = srt[js];
    atomicAdd(ws + OFF_BV + n, aB);
    if (FIRST) atomicAdd(ws + OFF_CBI + n, aC);
  }
}

// combine: spatial conv (separable) + message/compat/update + next-iter q.
// Reads q halo from qsrc, writes new q to qdst (+F slot); resets BV[j]=0.
__global__ __launch_bounds__(256) void combine_kernel(const float* __restrict__ logits,
                                                      const float* __restrict__ Wsp,
                                                      const float* __restrict__ Wbi,
                                                      const float* __restrict__ Cm,
                                                      float* __restrict__ ws,
                                                      float* __restrict__ out,
                                                      const float* __restrict__ qsrc,
                                                      float* __restrict__ qdst){
  __shared__ float tq[46][48];
  __shared__ float tr[46][17];
  __shared__ float wt[TAPS];
  int tx = threadIdx.x & 15, ty = threadIdx.x >> 4;
  int bx = blockIdx.x % 6, by = blockIdx.x / 6;
  int x0 = bx*16, y0 = by*16;

  for (int idx = threadIdx.x; idx < 46*46; idx += 256){
    int ly = idx / 46, lx = idx % 46;
    int gy = y0 - RAD + ly, gx = x0 - RAD + lx;
    float v = 0.f;
    if (gy >= 0 && gy < Hh && gx >= 0 && gx < Ww) v = qsrc[gy*Ww + gx];
    tq[ly][lx] = v;
  }
  if (threadIdx.x < TAPS) wt[threadIdx.x] = ws[OFF_WTAB + threadIdx.x];
  __syncthreads();

  for (int idx = threadIdx.x; idx < 46*16; idx += 256){
    int ly = idx >> 4, lx = idx & 15;
    float in = 0.f;
    #pragma unroll
    for (int dx=0; dx<TAPS; dx++) in = fmaf(wt[dx], tq[ly][lx+dx], in);
    tr[ly][lx] = in;
  }
  __syncthreads();

  int y = y0 + ty, x = x0 + tx, j = y*Ww + x;
  float S = 0.f;
  #pragma unroll
  for (int dy=0; dy<TAPS; dy++) S = fmaf(wt[dy], tr[ty+dy][tx], S);

  float Bv = ws[OFF_BV + j];
  ws[OFF_BV + j] = 0.f;                       // reset for next iteration's atomics
  float Cb = ws[OFF_CBI + j];
  float nb  = 1.0f/(Cb + EPSV);
  float Csp = ws[OFF_ROWW + y] * ws[OFF_ROWW + x];
  float nsp = 1.0f/(Csp + EPSV);

  float sp0 = S*nsp,  sp1 = (Csp - S)*nsp;    // q1 = 1 - q0 identity
  float bi0 = Bv*nb,  bi1 = (Cb - Bv)*nb;

  float m0 = Wsp[0]*sp0 + Wsp[1]*sp1 + Wbi[0]*bi0 + Wbi[1]*bi1;
  float m1 = Wsp[2]*sp0 + Wsp[3]*sp1 + Wbi[2]*bi0 + Wbi[3]*bi1;
  float cm0 = Cm[0]*m0 + Cm[1]*m1;
  float cm1 = Cm[2]*m0 + Cm[3]*m1;

  float o0 = logits[j]        - cm0;
  float o1 = logits[NPIX + j] - cm1;
  out[j]        = o0;
  out[NPIX + j] = o1;

  float qn = 1.0f / (1.0f + __builtin_amdgcn_exp2f((o1-o0)*LOG2E));
  qdst[j] = qn;
  int js = ((const int*)ws)[OFF_INV + j];
  ws[OFF_F + (size_t)js*8 + 6] = qn;
}

extern "C" void kernel_launch(void* const* d_in, const int* in_sizes, int n_in,
                              void* d_out, int out_size, void* d_ws, size_t ws_size,
                              hipStream_t stream){
  const float* image  = (const float*)d_in[0];
  const float* logits = (const float*)d_in[1];
  const float* Wsp    = (const float*)d_in[2];
  const float* Wbi    = (const float*)d_in[3];
  const float* Cm     = (const float*)d_in[4];
  float* out = (float*)d_out;
  float* ws  = (float*)d_ws;

  float* qbuf[2] = { ws + OFF_Q0, ws + OFF_Q1 };

  prep_kernel<<<1, 256, 0, stream>>>(image, logits, ws);
  bil_kernel<1><<<GRIDB, 256, 0, stream>>>(ws);          // q-filter + colsum
  combine_kernel<<<36, 256, 0, stream>>>(logits, Wsp, Wbi, Cm, ws, out,
                                         qbuf[0], qbuf[1]);
  for (int t=1; t<5; ++t){
    bil_kernel<0><<<GRIDB, 256, 0, stream>>>(ws);
    combine_kernel<<<36, 256, 0, stream>>>(logits, Wsp, Wbi, Cm, ws, out,
                                           qbuf[t&1], qbuf[(t+1)&1]);
  }
}

// Round 10
// 299.523 us; speedup vs baseline: 2.2158x; 1.2550x over previous
//
#include <hip/hip_runtime.h>
#include <math.h>

#define Hh 96
#define Ww 96
#define NPIX 9216
#define RAD 15
#define TAPS 31
#define NCH 144            // chunks of 64 sorted pixels
#define NBIN 4096
#define GRIDB 1024         // bilateral blocks (4 waves each)
#define EPSV 1e-20f
#define LOG2E 1.4426950408889634f
#define CUT2 60.0f         // boxdist_h^2 > 60 => k < 2^-30 => safe to skip

// ---- ws layout (4-byte units), ~690 KB ----
#define OFF_F    0                 // 8*NPIX feat_sorted: h0..h4, a, q, pad
#define OFF_Q0   73728             // NPIX  q ping (original order)
#define OFF_Q1   82944             // NPIX  q pong
#define OFF_CBI  92160             // NPIX  bilateral colsum, ORIGINAL order
#define OFF_BV   101376            // NPIX  bilateral q-filter, ORIGINAL order
#define OFF_ROWW 110592            // 96
#define OFF_WTAB 110688            // 32
// int regions
#define OFF_HIST 110720            // 4096
#define OFF_BASE 114816            // 4096
#define OFF_INV  118912            // NPIX  orig n -> sorted pos
#define OFF_SRT  128128            // NPIX  sorted pos -> orig n
#define OFF_OFS  137344            // NCH+1
#define OFF_WORK 137489            // NCH*NCH flat worklist (jg<<8|c)

__device__ __forceinline__ int color_key(float r, float g, float b){
  int rq = min(15, (int)r >> 4);
  int gq = min(15, (int)g >> 4);
  int bq = min(15, (int)b >> 4);
  int key = 0;
  #pragma unroll
  for (int k=0;k<4;k++){
    key |= ((rq>>k)&1) << (3*k+2);
    key |= ((gq>>k)&1) << (3*k+1);
    key |= ((bq>>k)&1) << (3*k);
  }
  return key;
}

// A: zero BV/CBI/hist + spatial tables
__global__ __launch_bounds__(256) void prepA_kernel(float* __restrict__ ws){
  int idx = blockIdx.x*256 + threadIdx.x;
  int* W = (int*)ws;
  if (idx < NPIX){ ws[OFF_BV+idx]=0.f; ws[OFF_CBI+idx]=0.f; }
  if (idx < NBIN) W[OFF_HIST+idx] = 0;
  if (blockIdx.x == 94 && threadIdx.x < Hh){
    int t = threadIdx.x;
    float s = 0.f;
    for (int yy=0; yy<Hh; ++yy){ float d=(float)(yy-t); s += expf(-d*d*(1.0f/18.0f)); }
    ws[OFF_ROWW + t] = s;                 // full 1-D colsum (spatial norm)
  }
  if (blockIdx.x == 95 && threadIdx.x < TAPS){
    int d = threadIdx.x - RAD;
    ws[OFF_WTAB + threadIdx.x] = expf(-(float)(d*d)*(1.0f/18.0f));
  }
}

// B: color histogram (global atomics, 36 blocks)
__global__ __launch_bounds__(256) void prepB_kernel(const float* __restrict__ image,
                                                    float* __restrict__ ws){
  int n = blockIdx.x*256 + threadIdx.x;
  int key = color_key(image[n], image[NPIX+n], image[2*NPIX+n]);
  atomicAdd((int*)ws + OFF_HIST + key, 1);
}

// C: exclusive scan of 4096 bins (1 block)
__global__ __launch_bounds__(256) void prepC_kernel(float* __restrict__ ws){
  __shared__ int part[256];
  const int* hist = (const int*)ws + OFF_HIST;
  int* base = (int*)ws + OFF_BASE;
  int t = threadIdx.x;
  int loc[16]; int s = 0;
  #pragma unroll
  for (int i=0;i<16;i++){ loc[i]=s; s += hist[t*16+i]; }
  part[t] = s; __syncthreads();
  for (int off=1; off<256; off<<=1){
    int v = (t>=off) ? part[t-off] : 0;
    __syncthreads(); part[t] += v; __syncthreads();
  }
  int b = (t==0)?0:part[t-1];
  #pragma unroll
  for (int i=0;i<16;i++) base[t*16+i] = b + loc[i];
}

// D: scatter + sorted feature build + initial softmax q
__global__ __launch_bounds__(256) void prepD_kernel(const float* __restrict__ image,
                                                    const float* __restrict__ logits,
                                                    float* __restrict__ ws){
  int n = blockIdx.x*256 + threadIdx.x;
  int* W = (int*)ws;
  float r=image[n], g=image[NPIX+n], bl=image[2*NPIX+n];
  int key = color_key(r,g,bl);
  int pos = atomicAdd(W + OFF_BASE + key, 1);
  W[OFF_INV + n] = pos;
  W[OFF_SRT + pos] = n;
  int y=n/Ww, x=n%Ww;
  const float c=0.7213475205f;    // 0.5/ln2
  const float sc=1.2011224088f;   // sqrt(2c)
  float f0=(float)y*(1.f/160.f), f1=(float)x*(1.f/160.f);
  float f2=r*(1.f/3.f), f3=g*(1.f/3.f), f4=bl*(1.f/3.f);
  float a=c*(f0*f0+f1*f1+f2*f2+f3*f3+f4*f4);
  float q = 1.f/(1.f + __builtin_amdgcn_exp2f((logits[NPIX+n]-logits[n])*LOG2E));
  float* F = ws + OFF_F + (size_t)pos*8;
  F[0]=sc*f0; F[1]=sc*f1; F[2]=sc*f2; F[3]=sc*f3; F[4]=sc*f4;
  F[5]=a; F[6]=q; F[7]=0.f;
  ws[OFF_Q0 + n] = q;
}

// E: bbox (LDS) + two-pass cull + direct pack into flat worklist (1 block)
__global__ __launch_bounds__(256) void prepE_kernel(float* __restrict__ ws){
  __shared__ float bb[NCH][12];
  __shared__ int cnt[NCH];
  __shared__ int ofs[NCH+1];
  __shared__ int part[256];
  const int t = threadIdx.x, lane = t & 63, wid = t >> 6;
  int* W = (int*)ws;
  const float* F = ws + OFF_F;

  // per-chunk 5-D bbox
  for (int ch = wid; ch < NCH; ch += 4){
    const float* Fp = F + ((size_t)ch*64 + lane)*8;
    float4 A = *(const float4*)Fp;
    float4 B4 = *(const float4*)(Fp+4);
    float mn[5]={A.x,A.y,A.z,A.w,B4.x}, mx[5]={A.x,A.y,A.z,A.w,B4.x};
    #pragma unroll
    for (int m=32; m; m>>=1){
      #pragma unroll
      for (int d=0;d<5;d++){
        mn[d]=fminf(mn[d], __shfl_xor(mn[d], m));
        mx[d]=fmaxf(mx[d], __shfl_xor(mx[d], m));
      }
    }
    if (lane == 0){
      #pragma unroll
      for (int d=0;d<5;d++){ bb[ch][d]=mn[d]; bb[ch][5+d]=mx[d]; }
    }
  }
  __syncthreads();

  // pass 1: survivor counts per j-group (wave = jg)
  for (int jg = wid; jg < NCH; jg += 4){
    int base = 0;
    #pragma unroll
    for (int r2=0;r2<3;r2++){
      int c2 = lane + 64*r2;
      bool sv = false;
      if (c2 < NCH){
        float s2 = 0.f;
        #pragma unroll
        for (int d=0;d<5;d++){
          float gap = fmaxf(0.f, fmaxf(bb[c2][d]-bb[jg][5+d], bb[jg][d]-bb[c2][5+d]));
          s2 = fmaf(gap, gap, s2);
        }
        sv = (s2 <= CUT2);
      }
      base += __popcll(__ballot(sv));
    }
    if (lane == 0) cnt[jg] = base;
  }
  __syncthreads();

  // exclusive scan of cnt -> ofs
  {
    int v = (t < NCH) ? cnt[t] : 0;
    part[t] = v; __syncthreads();
    for (int off=1; off<256; off<<=1){
      int u = (t>=off) ? part[t-off] : 0;
      __syncthreads(); part[t] += u; __syncthreads();
    }
    if (t == 0) ofs[0] = 0;
    ofs[t+1 <= NCH ? t+1 : NCH] = part[t < NCH ? t : NCH-1]; // ofs[t+1]=incl[t]
    __syncthreads();
    if (t <= NCH) W[OFF_OFS + t] = ofs[t];
  }
  __syncthreads();

  // pass 2: recompute survivors, pack directly at work[ofs[jg]+pos]
  for (int jg = wid; jg < NCH; jg += 4){
    int base = ofs[jg];
    #pragma unroll
    for (int r2=0;r2<3;r2++){
      int c2 = lane + 64*r2;
      bool sv = false;
      if (c2 < NCH){
        float s2 = 0.f;
        #pragma unroll
        for (int d=0;d<5;d++){
          float gap = fmaxf(0.f, fmaxf(bb[c2][d]-bb[jg][5+d], bb[jg][d]-bb[c2][5+d]));
          s2 = fmaf(gap, gap, s2);
        }
        sv = (s2 <= CUT2);
      }
      unsigned long long m = __ballot(sv);
      if (sv){
        int pos = __popcll(m & ((1ull<<lane)-1ull));
        W[OFF_WORK + base + pos] = (jg<<8) | c2;
      }
      base += __popcll(m);
    }
  }
}

// one WAVE per (jg,chunk) item; chunk staged in LDS; dual exp chains;
// atomic commit into ORIGINAL-order BV (+CBI when FIRST).
template<int FIRST>
__global__ __launch_bounds__(256) void bil_kernel(float* __restrict__ ws){
  __shared__ float chunk[4][512];
  const int lane = threadIdx.x & 63, wid = threadIdx.x >> 6;
  const int* W = (const int*)ws;
  const int T = W[OFF_OFS + NCH];
  const int* work = W + OFF_WORK;
  const int* srt  = W + OFF_SRT;
  const float* F  = ws + OFF_F;
  float* s = &chunk[wid][0];
  for (int it = blockIdx.x*4 + wid; it < T; it += GRIDB*4){
    int en = work[it];
    int jg = en >> 8, c = en & 255;
    int js = jg*64 + lane;
    float4 A  = *(const float4*)(F + (size_t)js*8);
    float4 B4 = *(const float4*)(F + (size_t)js*8 + 4);
    // stage chunk c (2 KB) into this wave's LDS quarter — coalesced
    const float* src = F + (size_t)c*512;
    *(float4*)(s + lane*8)     = *(const float4*)(src + lane*8);
    *(float4*)(s + lane*8 + 4) = *(const float4*)(src + lane*8 + 4);
    float h0=A.x,h1=A.y,h2=A.z,h3=A.w,h4=B4.x,na=-B4.y;
    float aB0=0.f,aB1=0.f,aC0=0.f,aC1=0.f;
    #pragma unroll 4
    for (int ii=0; ii<32; ii++){
      float4 w0 = *(const float4*)(s + ii*8);
      float4 w1 = *(const float4*)(s + ii*8 + 4);
      float e0 = na - w1.y;
      e0=fmaf(h0,w0.x,e0); e0=fmaf(h1,w0.y,e0); e0=fmaf(h2,w0.z,e0);
      e0=fmaf(h3,w0.w,e0); e0=fmaf(h4,w1.x,e0);
      float k0 = __builtin_amdgcn_exp2f(e0);
      aB0 = fmaf(k0, w1.z, aB0);
      if (FIRST) aC0 += k0;
      float4 u0 = *(const float4*)(s + 256 + ii*8);
      float4 u1 = *(const float4*)(s + 256 + ii*8 + 4);
      float e1 = na - u1.y;
      e1=fmaf(h0,u0.x,e1); e1=fmaf(h1,u0.y,e1); e1=fmaf(h2,u0.z,e1);
      e1=fmaf(h3,u0.w,e1); e1=fmaf(h4,u1.x,e1);
      float k1 = __builtin_amdgcn_exp2f(e1);
      aB1 = fmaf(k1, u1.z, aB1);
      if (FIRST) aC1 += k1;
    }
    int n = srt[js];
    atomicAdd(ws + OFF_BV + n, aB0 + aB1);
    if (FIRST) atomicAdd(ws + OFF_CBI + n, aC0 + aC1);
  }
}

// combine: separable spatial conv + message/compat/update + next-iter q.
// Reads q halo from qsrc, writes new q to qdst (+F slot); resets BV[j]=0.
__global__ __launch_bounds__(256) void combine_kernel(const float* __restrict__ logits,
                                                      const float* __restrict__ Wsp,
                                                      const float* __restrict__ Wbi,
                                                      const float* __restrict__ Cm,
                                                      float* __restrict__ ws,
                                                      float* __restrict__ out,
                                                      const float* __restrict__ qsrc,
                                                      float* __restrict__ qdst){
  __shared__ float tq[46][48];
  __shared__ float tr[46][17];
  __shared__ float wt[TAPS];
  int tx = threadIdx.x & 15, ty = threadIdx.x >> 4;
  int bx = blockIdx.x % 6, by = blockIdx.x / 6;
  int x0 = bx*16, y0 = by*16;

  for (int idx = threadIdx.x; idx < 46*46; idx += 256){
    int ly = idx / 46, lx = idx % 46;
    int gy = y0 - RAD + ly, gx = x0 - RAD + lx;
    float v = 0.f;
    if (gy >= 0 && gy < Hh && gx >= 0 && gx < Ww) v = qsrc[gy*Ww + gx];
    tq[ly][lx] = v;
  }
  if (threadIdx.x < TAPS) wt[threadIdx.x] = ws[OFF_WTAB + threadIdx.x];
  __syncthreads();

  for (int idx = threadIdx.x; idx < 46*16; idx += 256){
    int ly = idx >> 4, lx = idx & 15;
    float in = 0.f;
    #pragma unroll
    for (int dx=0; dx<TAPS; dx++) in = fmaf(wt[dx], tq[ly][lx+dx], in);
    tr[ly][lx] = in;
  }
  __syncthreads();

  int y = y0 + ty, x = x0 + tx, j = y*Ww + x;
  float S = 0.f;
  #pragma unroll
  for (int dy=0; dy<TAPS; dy++) S = fmaf(wt[dy], tr[ty+dy][tx], S);

  float Bv = ws[OFF_BV + j];
  ws[OFF_BV + j] = 0.f;                       // reset for next iteration's atomics
  float Cb = ws[OFF_CBI + j];
  float nb  = 1.0f/(Cb + EPSV);
  float Csp = ws[OFF_ROWW + y] * ws[OFF_ROWW + x];
  float nsp = 1.0f/(Csp + EPSV);

  float sp0 = S*nsp,  sp1 = (Csp - S)*nsp;    // q1 = 1 - q0 identity
  float bi0 = Bv*nb,  bi1 = (Cb - Bv)*nb;

  float m0 = Wsp[0]*sp0 + Wsp[1]*sp1 + Wbi[0]*bi0 + Wbi[1]*bi1;
  float m1 = Wsp[2]*sp0 + Wsp[3]*sp1 + Wbi[2]*bi0 + Wbi[3]*bi1;
  float cm0 = Cm[0]*m0 + Cm[1]*m1;
  float cm1 = Cm[2]*m0 + Cm[3]*m1;

  float o0 = logits[j]        - cm0;
  float o1 = logits[NPIX + j] - cm1;
  out[j]        = o0;
  out[NPIX + j] = o1;

  float qn = 1.0f / (1.0f + __builtin_amdgcn_exp2f((o1-o0)*LOG2E));
  qdst[j] = qn;
  int js = ((const int*)ws)[OFF_INV + j];
  ws[OFF_F + (size_t)js*8 + 6] = qn;
}

extern "C" void kernel_launch(void* const* d_in, const int* in_sizes, int n_in,
                              void* d_out, int out_size, void* d_ws, size_t ws_size,
                              hipStream_t stream){
  const float* image  = (const float*)d_in[0];
  const float* logits = (const float*)d_in[1];
  const float* Wsp    = (const float*)d_in[2];
  const float* Wbi    = (const float*)d_in[3];
  const float* Cm     = (const float*)d_in[4];
  float* out = (float*)d_out;
  float* ws  = (float*)d_ws;

  float* qbuf[2] = { ws + OFF_Q0, ws + OFF_Q1 };

  prepA_kernel<<<96, 256, 0, stream>>>(ws);
  prepB_kernel<<<36, 256, 0, stream>>>(image, ws);
  prepC_kernel<<<1, 256, 0, stream>>>(ws);
  prepD_kernel<<<36, 256, 0, stream>>>(image, logits, ws);
  prepE_kernel<<<1, 256, 0, stream>>>(ws);

  bil_kernel<1><<<GRIDB, 256, 0, stream>>>(ws);          // q-filter + colsum
  combine_kernel<<<36, 256, 0, stream>>>(logits, Wsp, Wbi, Cm, ws, out,
                                         qbuf[0], qbuf[1]);
  for (int t=1; t<5; ++t){
    bil_kernel<0><<<GRIDB, 256, 0, stream>>>(ws);
    combine_kernel<<<36, 256, 0, stream>>>(logits, Wsp, Wbi, Cm, ws, out,
                                           qbuf[t&1], qbuf[(t+1)&1]);
  }
}

// Round 11
// 222.108 us; speedup vs baseline: 2.9881x; 1.3485x over previous
//
#include <hip/hip_runtime.h>
#include <math.h>

#define Hh 96
#define Ww 96
#define NPIX 9216
#define RAD 15
#define TAPS 31
#define NCH 144            // chunks of 64 sorted pixels
#define NBIN 4096
#define GRIDB 2048         // bilateral blocks (4 waves each)
#define EPSV 1e-20f
#define LOG2E 1.4426950408889634f
#define CUT2 60.0f         // box-box prune (build time)
#define PCUT2 42.0f        // point-box prune (run time): c*42 > 30 bits

// ---- ws layout (4-byte units), ~690 KB ----
#define OFF_F    0                 // 8*NPIX feat_sorted: h0..h4, a, q, pad
#define OFF_Q0   73728             // NPIX  q ping (original order)
#define OFF_Q1   82944             // NPIX  q pong
#define OFF_CBI  92160             // NPIX  bilateral colsum, ORIGINAL order
#define OFF_BV   101376            // NPIX  bilateral q-filter, ORIGINAL order
#define OFF_ROWW 110592            // 96
#define OFF_WTAB 110688            // 32
#define OFF_BBOX 110720            // NCH*12 (min[5],max[5],pad2)
// int regions
#define OFF_HIST 112448            // 4096
#define OFF_BASE 116544            // 4096
#define OFF_INV  120640            // NPIX  orig n -> sorted pos
#define OFF_SRT  129856            // NPIX  sorted pos -> orig n
#define OFF_OFS  139072            // NCH+1
#define OFF_WORK 139217            // NCH*NCH flat worklist (jg<<8|c)

__device__ __forceinline__ int color_key(float r, float g, float b){
  int rq = min(15, (int)r >> 4);
  int gq = min(15, (int)g >> 4);
  int bq = min(15, (int)b >> 4);
  int key = 0;
  #pragma unroll
  for (int k=0;k<4;k++){
    key |= ((rq>>k)&1) << (3*k+2);
    key |= ((gq>>k)&1) << (3*k+1);
    key |= ((bq>>k)&1) << (3*k);
  }
  return key;
}

// A: zero BV/CBI/hist + spatial tables
__global__ __launch_bounds__(256) void prepA_kernel(float* __restrict__ ws){
  int idx = blockIdx.x*256 + threadIdx.x;
  int* W = (int*)ws;
  if (idx < NPIX){ ws[OFF_BV+idx]=0.f; ws[OFF_CBI+idx]=0.f; }
  if (idx < NBIN) W[OFF_HIST+idx] = 0;
  if (blockIdx.x == 94 && threadIdx.x < Hh){
    int t = threadIdx.x;
    float s = 0.f;
    for (int yy=0; yy<Hh; ++yy){ float d=(float)(yy-t); s += expf(-d*d*(1.0f/18.0f)); }
    ws[OFF_ROWW + t] = s;                 // full 1-D colsum (spatial norm)
  }
  if (blockIdx.x == 95 && threadIdx.x < TAPS){
    int d = threadIdx.x - RAD;
    ws[OFF_WTAB + threadIdx.x] = expf(-(float)(d*d)*(1.0f/18.0f));
  }
}

// B: color histogram
__global__ __launch_bounds__(256) void prepB_kernel(const float* __restrict__ image,
                                                    float* __restrict__ ws){
  int n = blockIdx.x*256 + threadIdx.x;
  int key = color_key(image[n], image[NPIX+n], image[2*NPIX+n]);
  atomicAdd((int*)ws + OFF_HIST + key, 1);
}

// C: exclusive scan of 4096 bins (1 block)
__global__ __launch_bounds__(256) void prepC_kernel(float* __restrict__ ws){
  __shared__ int part[256];
  const int* hist = (const int*)ws + OFF_HIST;
  int* base = (int*)ws + OFF_BASE;
  int t = threadIdx.x;
  int loc[16]; int s = 0;
  #pragma unroll
  for (int i=0;i<16;i++){ loc[i]=s; s += hist[t*16+i]; }
  part[t] = s; __syncthreads();
  for (int off=1; off<256; off<<=1){
    int v = (t>=off) ? part[t-off] : 0;
    __syncthreads(); part[t] += v; __syncthreads();
  }
  int b = (t==0)?0:part[t-1];
  #pragma unroll
  for (int i=0;i<16;i++) base[t*16+i] = b + loc[i];
}

// D: scatter + sorted feature build + initial softmax q
__global__ __launch_bounds__(256) void prepD_kernel(const float* __restrict__ image,
                                                    const float* __restrict__ logits,
                                                    float* __restrict__ ws){
  int n = blockIdx.x*256 + threadIdx.x;
  int* W = (int*)ws;
  float r=image[n], g=image[NPIX+n], bl=image[2*NPIX+n];
  int key = color_key(r,g,bl);
  int pos = atomicAdd(W + OFF_BASE + key, 1);
  W[OFF_INV + n] = pos;
  W[OFF_SRT + pos] = n;
  int y=n/Ww, x=n%Ww;
  const float c=0.7213475205f;    // 0.5/ln2
  const float sc=1.2011224088f;   // sqrt(2c)
  float f0=(float)y*(1.f/160.f), f1=(float)x*(1.f/160.f);
  float f2=r*(1.f/3.f), f3=g*(1.f/3.f), f4=bl*(1.f/3.f);
  float a=c*(f0*f0+f1*f1+f2*f2+f3*f3+f4*f4);
  float q = 1.f/(1.f + __builtin_amdgcn_exp2f((logits[NPIX+n]-logits[n])*LOG2E));
  float* F = ws + OFF_F + (size_t)pos*8;
  F[0]=sc*f0; F[1]=sc*f1; F[2]=sc*f2; F[3]=sc*f3; F[4]=sc*f4;
  F[5]=a; F[6]=q; F[7]=0.f;
  ws[OFF_Q0 + n] = q;
}

// E1: per-chunk 5-D bbox, one wave per chunk (36 blocks x 4 waves = 144)
__global__ __launch_bounds__(256) void prepE1_kernel(float* __restrict__ ws){
  const int lane = threadIdx.x & 63, wid = threadIdx.x >> 6;
  int ch = blockIdx.x*4 + wid;
  if (ch >= NCH) return;
  const float* Fp = ws + OFF_F + ((size_t)ch*64 + lane)*8;
  float4 A = *(const float4*)Fp;
  float4 B4 = *(const float4*)(Fp+4);
  float mn[5]={A.x,A.y,A.z,A.w,B4.x}, mx[5]={A.x,A.y,A.z,A.w,B4.x};
  #pragma unroll
  for (int m=32; m; m>>=1){
    #pragma unroll
    for (int d=0;d<5;d++){
      mn[d]=fminf(mn[d], __shfl_xor(mn[d], m));
      mx[d]=fmaxf(mx[d], __shfl_xor(mx[d], m));
    }
  }
  if (lane == 0){
    float* bb = ws + OFF_BBOX + ch*12;
    #pragma unroll
    for (int d=0;d<5;d++){ bb[d]=mn[d]; bb[5+d]=mx[d]; }
  }
}

// E2: cull (box-box) + scan + pack flat worklist (1 block, all LDS)
__global__ __launch_bounds__(256) void prepE2_kernel(float* __restrict__ ws){
  __shared__ float bbl[NCH*12];
  __shared__ int cnt[NCH];
  __shared__ int part[256];
  const int t = threadIdx.x, lane = t & 63, wid = t >> 6;
  int* W = (int*)ws;

  for (int i=t; i<NCH*12; i+=256) bbl[i] = ws[OFF_BBOX + i];
  __syncthreads();

  // pass 1: survivor counts
  for (int jg = wid; jg < NCH; jg += 4){
    const float* jb = &bbl[jg*12];
    int base = 0;
    #pragma unroll
    for (int r2=0;r2<3;r2++){
      int c2 = lane + 64*r2;
      bool sv = false;
      if (c2 < NCH){
        const float* cb = &bbl[c2*12];
        float s2 = 0.f;
        #pragma unroll
        for (int d=0;d<5;d++){
          float gap = fmaxf(0.f, fmaxf(cb[d]-jb[5+d], jb[d]-cb[5+d]));
          s2 = fmaf(gap, gap, s2);
        }
        sv = (s2 <= CUT2);
      }
      base += __popcll(__ballot(sv));
    }
    if (lane == 0) cnt[jg] = base;
  }
  __syncthreads();

  // inclusive scan of cnt (zero-padded to 256)
  int v = (t < NCH) ? cnt[t] : 0;
  part[t] = v; __syncthreads();
  for (int off=1; off<256; off<<=1){
    int u = (t>=off) ? part[t-off] : 0;
    __syncthreads(); part[t] += u; __syncthreads();
  }
  if (t == 0) W[OFF_OFS] = 0;
  if (t < NCH) W[OFF_OFS + t + 1] = part[t];
  __syncthreads();

  // pass 2: recompute + pack at work[ofs[jg]+pos]
  for (int jg = wid; jg < NCH; jg += 4){
    const float* jb = &bbl[jg*12];
    int base = (jg == 0) ? 0 : part[jg-1];
    #pragma unroll
    for (int r2=0;r2<3;r2++){
      int c2 = lane + 64*r2;
      bool sv = false;
      if (c2 < NCH){
        const float* cb = &bbl[c2*12];
        float s2 = 0.f;
        #pragma unroll
        for (int d=0;d<5;d++){
          float gap = fmaxf(0.f, fmaxf(cb[d]-jb[5+d], jb[d]-cb[5+d]));
          s2 = fmaf(gap, gap, s2);
        }
        sv = (s2 <= CUT2);
      }
      unsigned long long m = __ballot(sv);
      if (sv){
        int pos = __popcll(m & ((1ull<<lane)-1ull));
        W[OFF_WORK + base + pos] = (jg<<8) | c2;
      }
      base += __popcll(m);
    }
  }
}

// one WAVE per (jg,chunk) item; point-to-box runtime prune; LDS-staged chunk;
// dual exp chains; atomic commit into ORIGINAL-order BV (+CBI when FIRST).
template<int FIRST>
__global__ __launch_bounds__(256) void bil_kernel(float* __restrict__ ws){
  __shared__ float chunk[4][512];
  const int lane = threadIdx.x & 63, wid = threadIdx.x >> 6;
  const int* W = (const int*)ws;
  const int T = W[OFF_OFS + NCH];
  const int* work = W + OFF_WORK;
  const int* srt  = W + OFF_SRT;
  const float* F  = ws + OFF_F;
  float* s = &chunk[wid][0];
  for (int it = blockIdx.x*4 + wid; it < T; it += GRIDB*4){
    int en = work[it];
    int jg = en >> 8, c = en & 255;
    int js = jg*64 + lane;
    float4 A  = *(const float4*)(F + (size_t)js*8);
    float4 B4 = *(const float4*)(F + (size_t)js*8 + 4);
    float h0=A.x,h1=A.y,h2=A.z,h3=A.w,h4=B4.x,na=-B4.y;

    // runtime prune: this j-point vs chunk c's bbox
    const float* cb = ws + OFF_BBOX + c*12;
    float g0 = fmaxf(0.f, fmaxf(cb[0]-h0, h0-cb[5]));
    float g1 = fmaxf(0.f, fmaxf(cb[1]-h1, h1-cb[6]));
    float g2 = fmaxf(0.f, fmaxf(cb[2]-h2, h2-cb[7]));
    float g3 = fmaxf(0.f, fmaxf(cb[3]-h3, h3-cb[8]));
    float g4 = fmaxf(0.f, fmaxf(cb[4]-h4, h4-cb[9]));
    float dd = g0*g0;
    dd = fmaf(g1,g1,dd); dd = fmaf(g2,g2,dd);
    dd = fmaf(g3,g3,dd); dd = fmaf(g4,g4,dd);
    if (!__any(dd <= PCUT2)) continue;     // whole wave beyond cutoff

    // stage chunk c (2 KB) into this wave's LDS quarter
    const float* src = F + (size_t)c*512;
    *(float4*)(s + lane*8)     = *(const float4*)(src + lane*8);
    *(float4*)(s + lane*8 + 4) = *(const float4*)(src + lane*8 + 4);

    float aB0=0.f,aB1=0.f,aC0=0.f,aC1=0.f;
    #pragma unroll 4
    for (int ii=0; ii<32; ii++){
      float4 w0 = *(const float4*)(s + ii*8);
      float4 w1 = *(const float4*)(s + ii*8 + 4);
      float e0 = na - w1.y;
      e0=fmaf(h0,w0.x,e0); e0=fmaf(h1,w0.y,e0); e0=fmaf(h2,w0.z,e0);
      e0=fmaf(h3,w0.w,e0); e0=fmaf(h4,w1.x,e0);
      float k0 = __builtin_amdgcn_exp2f(e0);
      aB0 = fmaf(k0, w1.z, aB0);
      if (FIRST) aC0 += k0;
      float4 u0 = *(const float4*)(s + 256 + ii*8);
      float4 u1 = *(const float4*)(s + 256 + ii*8 + 4);
      float e1 = na - u1.y;
      e1=fmaf(h0,u0.x,e1); e1=fmaf(h1,u0.y,e1); e1=fmaf(h2,u0.z,e1);
      e1=fmaf(h3,u0.w,e1); e1=fmaf(h4,u1.x,e1);
      float k1 = __builtin_amdgcn_exp2f(e1);
      aB1 = fmaf(k1, u1.z, aB1);
      if (FIRST) aC1 += k1;
    }
    int n = srt[js];
    atomicAdd(ws + OFF_BV + n, aB0 + aB1);
    if (FIRST) atomicAdd(ws + OFF_CBI + n, aC0 + aC1);
  }
}

// combine: separable spatial conv + message/compat/update + next-iter q.
__global__ __launch_bounds__(256) void combine_kernel(const float* __restrict__ logits,
                                                      const float* __restrict__ Wsp,
                                                      const float* __restrict__ Wbi,
                                                      const float* __restrict__ Cm,
                                                      float* __restrict__ ws,
                                                      float* __restrict__ out,
                                                      const float* __restrict__ qsrc,
                                                      float* __restrict__ qdst){
  __shared__ float tq[46][48];
  __shared__ float tr[46][17];
  __shared__ float wt[TAPS];
  int tx = threadIdx.x & 15, ty = threadIdx.x >> 4;
  int bx = blockIdx.x % 6, by = blockIdx.x / 6;
  int x0 = bx*16, y0 = by*16;

  for (int idx = threadIdx.x; idx < 46*46; idx += 256){
    int ly = idx / 46, lx = idx % 46;
    int gy = y0 - RAD + ly, gx = x0 - RAD + lx;
    float v = 0.f;
    if (gy >= 0 && gy < Hh && gx >= 0 && gx < Ww) v = qsrc[gy*Ww + gx];
    tq[ly][lx] = v;
  }
  if (threadIdx.x < TAPS) wt[threadIdx.x] = ws[OFF_WTAB + threadIdx.x];
  __syncthreads();

  for (int idx = threadIdx.x; idx < 46*16; idx += 256){
    int ly = idx >> 4, lx = idx & 15;
    float in = 0.f;
    #pragma unroll
    for (int dx=0; dx<TAPS; dx++) in = fmaf(wt[dx], tq[ly][lx+dx], in);
    tr[ly][lx] = in;
  }
  __syncthreads();

  int y = y0 + ty, x = x0 + tx, j = y*Ww + x;
  float S = 0.f;
  #pragma unroll
  for (int dy=0; dy<TAPS; dy++) S = fmaf(wt[dy], tr[ty+dy][tx], S);

  float Bv = ws[OFF_BV + j];
  ws[OFF_BV + j] = 0.f;                       // reset for next iteration's atomics
  float Cb = ws[OFF_CBI + j];
  float nb  = 1.0f/(Cb + EPSV);
  float Csp = ws[OFF_ROWW + y] * ws[OFF_ROWW + x];
  float nsp = 1.0f/(Csp + EPSV);

  float sp0 = S*nsp,  sp1 = (Csp - S)*nsp;    // q1 = 1 - q0 identity
  float bi0 = Bv*nb,  bi1 = (Cb - Bv)*nb;

  float m0 = Wsp[0]*sp0 + Wsp[1]*sp1 + Wbi[0]*bi0 + Wbi[1]*bi1;
  float m1 = Wsp[2]*sp0 + Wsp[3]*sp1 + Wbi[2]*bi0 + Wbi[3]*bi1;
  float cm0 = Cm[0]*m0 + Cm[1]*m1;
  float cm1 = Cm[2]*m0 + Cm[3]*m1;

  float o0 = logits[j]        - cm0;
  float o1 = logits[NPIX + j] - cm1;
  out[j]        = o0;
  out[NPIX + j] = o1;

  float qn = 1.0f / (1.0f + __builtin_amdgcn_exp2f((o1-o0)*LOG2E));
  qdst[j] = qn;
  int js = ((const int*)ws)[OFF_INV + j];
  ws[OFF_F + (size_t)js*8 + 6] = qn;
}

extern "C" void kernel_launch(void* const* d_in, const int* in_sizes, int n_in,
                              void* d_out, int out_size, void* d_ws, size_t ws_size,
                              hipStream_t stream){
  const float* image  = (const float*)d_in[0];
  const float* logits = (const float*)d_in[1];
  const float* Wsp    = (const float*)d_in[2];
  const float* Wbi    = (const float*)d_in[3];
  const float* Cm     = (const float*)d_in[4];
  float* out = (float*)d_out;
  float* ws  = (float*)d_ws;

  float* qbuf[2] = { ws + OFF_Q0, ws + OFF_Q1 };

  prepA_kernel <<<96, 256, 0, stream>>>(ws);
  prepB_kernel <<<36, 256, 0, stream>>>(image, ws);
  prepC_kernel <<<1, 256, 0, stream>>>(ws);
  prepD_kernel <<<36, 256, 0, stream>>>(image, logits, ws);
  prepE1_kernel<<<36, 256, 0, stream>>>(ws);
  prepE2_kernel<<<1, 256, 0, stream>>>(ws);

  bil_kernel<1><<<GRIDB, 256, 0, stream>>>(ws);          // q-filter + colsum
  combine_kernel<<<36, 256, 0, stream>>>(logits, Wsp, Wbi, Cm, ws, out,
                                         qbuf[0], qbuf[1]);
  for (int t=1; t<5; ++t){
    bil_kernel<0><<<GRIDB, 256, 0, stream>>>(ws);
    combine_kernel<<<36, 256, 0, stream>>>(logits, Wsp, Wbi, Cm, ws, out,
                                           qbuf[t&1], qbuf[(t+1)&1]);
  }
}

// Round 12
// 145.867 us; speedup vs baseline: 4.5499x; 1.5227x over previous
//
#include <hip/hip_runtime.h>
#include <hip/hip_fp16.h>
#include <math.h>

#define Hh 96
#define Ww 96
#define NPIX 9216
#define RAD 15
#define TAPS 31
#define NCH 144            // chunks of 64 sorted pixels
#define NBIN 4096
#define GRIDB 2048         // build/matvec blocks (4 waves each)
#define EPSV 1e-20f
#define LOG2E 1.4426950408889634f
#define CUT2 60.0f         // box-box prune: k < 2^-43 beyond => safe to skip

// ---- ws layout (4-byte units); total ~171 MB of the 256 MiB ws ----
#define OFF_F    0                 // 8*NPIX feat_sorted: h0..h4, a, pad2
#define OFF_Q0   73728             // NPIX  q ping (original order, combine halo)
#define OFF_Q1   82944             // NPIX  q pong
#define OFF_QS   92160             // NPIX  q SORTED order (matvec input)
#define OFF_CBI  101376            // NPIX  bilateral colsum, SORTED order
#define OFF_BV   110592            // NPIX  bilateral q-filter, SORTED order
#define OFF_ROWW 119808            // 96
#define OFF_WTAB 119904            // 32
#define OFF_BBOX 119936            // NCH*12
// int regions
#define OFF_HIST 121664            // 4096
#define OFF_BASE 125760            // 4096
#define OFF_INV  129856            // NPIX  orig n -> sorted pos
#define OFF_SRT  139072            // NPIX  sorted pos -> orig n
#define OFF_OFS  148288            // NCH+1
#define OFF_WORK 148433            // NCH*NCH flat worklist (jg<<8|c)
#define OFF_K    169984            // T*2048 u32: fp16 K blocks, [item][j][i]

__device__ __forceinline__ int color_key(float r, float g, float b){
  int rq = min(15, (int)r >> 4);
  int gq = min(15, (int)g >> 4);
  int bq = min(15, (int)b >> 4);
  int key = 0;
  #pragma unroll
  for (int k=0;k<4;k++){
    key |= ((rq>>k)&1) << (3*k+2);
    key |= ((gq>>k)&1) << (3*k+1);
    key |= ((bq>>k)&1) << (3*k);
  }
  return key;
}

// A: zero BV/CBI/hist + spatial tables
__global__ __launch_bounds__(256) void prepA_kernel(float* __restrict__ ws){
  int idx = blockIdx.x*256 + threadIdx.x;
  int* W = (int*)ws;
  if (idx < NPIX){ ws[OFF_BV+idx]=0.f; ws[OFF_CBI+idx]=0.f; }
  if (idx < NBIN) W[OFF_HIST+idx] = 0;
  if (blockIdx.x == 94 && threadIdx.x < Hh){
    int t = threadIdx.x;
    float s = 0.f;
    for (int yy=0; yy<Hh; ++yy){ float d=(float)(yy-t); s += expf(-d*d*(1.0f/18.0f)); }
    ws[OFF_ROWW + t] = s;                 // full 1-D colsum (spatial norm)
  }
  if (blockIdx.x == 95 && threadIdx.x < TAPS){
    int d = threadIdx.x - RAD;
    ws[OFF_WTAB + threadIdx.x] = expf(-(float)(d*d)*(1.0f/18.0f));
  }
}

// B: color histogram
__global__ __launch_bounds__(256) void prepB_kernel(const float* __restrict__ image,
                                                    float* __restrict__ ws){
  int n = blockIdx.x*256 + threadIdx.x;
  int key = color_key(image[n], image[NPIX+n], image[2*NPIX+n]);
  atomicAdd((int*)ws + OFF_HIST + key, 1);
}

// C: exclusive scan of 4096 bins (1 block)
__global__ __launch_bounds__(256) void prepC_kernel(float* __restrict__ ws){
  __shared__ int part[256];
  const int* hist = (const int*)ws + OFF_HIST;
  int* base = (int*)ws + OFF_BASE;
  int t = threadIdx.x;
  int loc[16]; int s = 0;
  #pragma unroll
  for (int i=0;i<16;i++){ loc[i]=s; s += hist[t*16+i]; }
  part[t] = s; __syncthreads();
  for (int off=1; off<256; off<<=1){
    int v = (t>=off) ? part[t-off] : 0;
    __syncthreads(); part[t] += v; __syncthreads();
  }
  int b = (t==0)?0:part[t-1];
  #pragma unroll
  for (int i=0;i<16;i++) base[t*16+i] = b + loc[i];
}

// D: scatter + sorted feature build + initial softmax q (orig + sorted)
__global__ __launch_bounds__(256) void prepD_kernel(const float* __restrict__ image,
                                                    const float* __restrict__ logits,
                                                    float* __restrict__ ws){
  int n = blockIdx.x*256 + threadIdx.x;
  int* W = (int*)ws;
  float r=image[n], g=image[NPIX+n], bl=image[2*NPIX+n];
  int key = color_key(r,g,bl);
  int pos = atomicAdd(W + OFF_BASE + key, 1);
  W[OFF_INV + n] = pos;
  W[OFF_SRT + pos] = n;
  int y=n/Ww, x=n%Ww;
  const float c=0.7213475205f;    // 0.5/ln2
  const float sc=1.2011224088f;   // sqrt(2c)
  float f0=(float)y*(1.f/160.f), f1=(float)x*(1.f/160.f);
  float f2=r*(1.f/3.f), f3=g*(1.f/3.f), f4=bl*(1.f/3.f);
  float a=c*(f0*f0+f1*f1+f2*f2+f3*f3+f4*f4);
  float q = 1.f/(1.f + __builtin_amdgcn_exp2f((logits[NPIX+n]-logits[n])*LOG2E));
  float* F = ws + OFF_F + (size_t)pos*8;
  F[0]=sc*f0; F[1]=sc*f1; F[2]=sc*f2; F[3]=sc*f3; F[4]=sc*f4;
  F[5]=a; F[6]=0.f; F[7]=0.f;
  ws[OFF_Q0 + n] = q;
  ws[OFF_QS + pos] = q;
}

// E1: per-chunk 5-D bbox, one wave per chunk
__global__ __launch_bounds__(256) void prepE1_kernel(float* __restrict__ ws){
  const int lane = threadIdx.x & 63, wid = threadIdx.x >> 6;
  int ch = blockIdx.x*4 + wid;
  if (ch >= NCH) return;
  const float* Fp = ws + OFF_F + ((size_t)ch*64 + lane)*8;
  float4 A = *(const float4*)Fp;
  float4 B4 = *(const float4*)(Fp+4);
  float mn[5]={A.x,A.y,A.z,A.w,B4.x}, mx[5]={A.x,A.y,A.z,A.w,B4.x};
  #pragma unroll
  for (int m=32; m; m>>=1){
    #pragma unroll
    for (int d=0;d<5;d++){
      mn[d]=fminf(mn[d], __shfl_xor(mn[d], m));
      mx[d]=fmaxf(mx[d], __shfl_xor(mx[d], m));
    }
  }
  if (lane == 0){
    float* bb = ws + OFF_BBOX + ch*12;
    #pragma unroll
    for (int d=0;d<5;d++){ bb[d]=mn[d]; bb[5+d]=mx[d]; }
  }
}

// E2: cull (box-box) + scan + pack flat worklist (1 block, all LDS)
__global__ __launch_bounds__(256) void prepE2_kernel(float* __restrict__ ws){
  __shared__ float bbl[NCH*12];
  __shared__ int part[256];
  const int t = threadIdx.x, lane = t & 63, wid = t >> 6;
  int* W = (int*)ws;

  for (int i=t; i<NCH*12; i+=256) bbl[i] = ws[OFF_BBOX + i];
  __syncthreads();

  __shared__ int cnt[NCH];
  for (int jg = wid; jg < NCH; jg += 4){
    const float* jb = &bbl[jg*12];
    int base = 0;
    #pragma unroll
    for (int r2=0;r2<3;r2++){
      int c2 = lane + 64*r2;
      bool sv = false;
      if (c2 < NCH){
        const float* cb = &bbl[c2*12];
        float s2 = 0.f;
        #pragma unroll
        for (int d=0;d<5;d++){
          float gap = fmaxf(0.f, fmaxf(cb[d]-jb[5+d], jb[d]-cb[5+d]));
          s2 = fmaf(gap, gap, s2);
        }
        sv = (s2 <= CUT2);
      }
      base += __popcll(__ballot(sv));
    }
    if (lane == 0) cnt[jg] = base;
  }
  __syncthreads();

  int v = (t < NCH) ? cnt[t] : 0;
  part[t] = v; __syncthreads();
  for (int off=1; off<256; off<<=1){
    int u = (t>=off) ? part[t-off] : 0;
    __syncthreads(); part[t] += u; __syncthreads();
  }
  if (t == 0) W[OFF_OFS] = 0;
  if (t < NCH) W[OFF_OFS + t + 1] = part[t];
  __syncthreads();

  for (int jg = wid; jg < NCH; jg += 4){
    const float* jb = &bbl[jg*12];
    int base = (jg == 0) ? 0 : part[jg-1];
    #pragma unroll
    for (int r2=0;r2<3;r2++){
      int c2 = lane + 64*r2;
      bool sv = false;
      if (c2 < NCH){
        const float* cb = &bbl[c2*12];
        float s2 = 0.f;
        #pragma unroll
        for (int d=0;d<5;d++){
          float gap = fmaxf(0.f, fmaxf(cb[d]-jb[5+d], jb[d]-cb[5+d]));
          s2 = fmaf(gap, gap, s2);
        }
        sv = (s2 <= CUT2);
      }
      unsigned long long m = __ballot(sv);
      if (sv){
        int pos = __popcll(m & ((1ull<<lane)-1ull));
        W[OFF_WORK + base + pos] = (jg<<8) | c2;
      }
      base += __popcll(m);
    }
  }
}

// buildK: one wave per (jg,chunk) item. Computes k for all 64 i,
// packs fp16 K[item][j][i] (lane j owns contiguous 128B), accumulates
// colsum -> CBI and the t=0 q-filter -> BV (both sorted order, coalesced atomics).
__global__ __launch_bounds__(256) void buildK_kernel(float* __restrict__ ws){
  __shared__ float chunk[4][512];
  __shared__ float qsh[4][64];
  const int lane = threadIdx.x & 63, wid = threadIdx.x >> 6;
  int* W = (int*)ws;
  const int T = W[OFF_OFS + NCH];
  const int* work = W + OFF_WORK;
  const float* F  = ws + OFF_F;
  float* s = &chunk[wid][0];
  float* ql = &qsh[wid][0];
  for (int it = blockIdx.x*4 + wid; it < T; it += GRIDB*4){
    int en = work[it];
    int jg = en >> 8, c = en & 255;
    int js = jg*64 + lane;
    float4 A  = *(const float4*)(F + (size_t)js*8);
    float4 B4 = *(const float4*)(F + (size_t)js*8 + 4);
    float h0=A.x,h1=A.y,h2=A.z,h3=A.w,h4=B4.x,na=-B4.y;
    // stage chunk c features (2KB) + its q (256B) into wave-private LDS
    const float* src = F + (size_t)c*512;
    *(float4*)(s + lane*8)     = *(const float4*)(src + lane*8);
    *(float4*)(s + lane*8 + 4) = *(const float4*)(src + lane*8 + 4);
    ql[lane] = ws[OFF_QS + c*64 + lane];

    unsigned int kp[32];
    float aB=0.f, aC=0.f;
    #pragma unroll 4
    for (int ii=0; ii<32; ii++){
      float4 w0 = *(const float4*)(s + 2*ii*8);
      float4 w1 = *(const float4*)(s + 2*ii*8 + 4);
      float e0 = na - w1.y;
      e0=fmaf(h0,w0.x,e0); e0=fmaf(h1,w0.y,e0); e0=fmaf(h2,w0.z,e0);
      e0=fmaf(h3,w0.w,e0); e0=fmaf(h4,w1.x,e0);
      float k0 = __builtin_amdgcn_exp2f(e0);
      float4 u0 = *(const float4*)(s + (2*ii+1)*8);
      float4 u1 = *(const float4*)(s + (2*ii+1)*8 + 4);
      float e1 = na - u1.y;
      e1=fmaf(h0,u0.x,e1); e1=fmaf(h1,u0.y,e1); e1=fmaf(h2,u0.z,e1);
      e1=fmaf(h3,u0.w,e1); e1=fmaf(h4,u1.x,e1);
      float k1 = __builtin_amdgcn_exp2f(e1);
      aC += k0 + k1;
      aB = fmaf(k0, ql[2*ii],   aB);
      aB = fmaf(k1, ql[2*ii+1], aB);
      __half2 h2v = __floats2half2_rn(k0, k1);
      kp[ii] = *reinterpret_cast<unsigned int*>(&h2v);
    }
    unsigned int* Kp = (unsigned int*)ws + OFF_K + (size_t)it*2048 + lane*32;
    #pragma unroll
    for (int r=0;r<8;r++)
      *(uint4*)(Kp + r*4) = make_uint4(kp[4*r],kp[4*r+1],kp[4*r+2],kp[4*r+3]);
    atomicAdd(ws + OFF_BV  + js, aB);
    atomicAdd(ws + OFF_CBI + js, aC);
  }
}

// matvec: one wave per item; stream 8KB fp16 K block (independent uint4 loads),
// q broadcast from LDS, fp32 accumulate, coalesced atomic commit (sorted BV).
__global__ __launch_bounds__(256) void matvec_kernel(float* __restrict__ ws){
  __shared__ float qsh[4][64];
  const int lane = threadIdx.x & 63, wid = threadIdx.x >> 6;
  const int* W = (const int*)ws;
  const int T = W[OFF_OFS + NCH];
  const int* work = W + OFF_WORK;
  float* ql = &qsh[wid][0];
  for (int it = blockIdx.x*4 + wid; it < T; it += GRIDB*4){
    int en = work[it];
    int jg = en >> 8, c = en & 255;
    int js = jg*64 + lane;
    ql[lane] = ws[OFF_QS + c*64 + lane];
    const unsigned int* Kp = (const unsigned int*)ws + OFF_K + (size_t)it*2048 + lane*32;
    float acc0=0.f, acc1=0.f;
    #pragma unroll
    for (int r=0;r<8;r++){
      uint4 p = *(const uint4*)(Kp + r*4);
      float4 qa = *(const float4*)(ql + r*8);
      float4 qb = *(const float4*)(ql + r*8 + 4);
      __half2 h;
      h = *reinterpret_cast<__half2*>(&p.x);
      acc0 = fmaf(__low2float(h), qa.x, acc0); acc1 = fmaf(__high2float(h), qa.y, acc1);
      h = *reinterpret_cast<__half2*>(&p.y);
      acc0 = fmaf(__low2float(h), qa.z, acc0); acc1 = fmaf(__high2float(h), qa.w, acc1);
      h = *reinterpret_cast<__half2*>(&p.z);
      acc0 = fmaf(__low2float(h), qb.x, acc0); acc1 = fmaf(__high2float(h), qb.y, acc1);
      h = *reinterpret_cast<__half2*>(&p.w);
      acc0 = fmaf(__low2float(h), qb.z, acc0); acc1 = fmaf(__high2float(h), qb.w, acc1);
    }
    atomicAdd(ws + OFF_BV + js, acc0 + acc1);
  }
}

// combine: separable spatial conv + message/compat/update + next-iter q.
// Reads BV/CBI (sorted) via INV, resets BV; writes q to pong buffer + QS.
__global__ __launch_bounds__(256) void combine_kernel(const float* __restrict__ logits,
                                                      const float* __restrict__ Wsp,
                                                      const float* __restrict__ Wbi,
                                                      const float* __restrict__ Cm,
                                                      float* __restrict__ ws,
                                                      float* __restrict__ out,
                                                      const float* __restrict__ qsrc,
                                                      float* __restrict__ qdst){
  __shared__ float tq[46][48];
  __shared__ float tr[46][17];
  __shared__ float wt[TAPS];
  int tx = threadIdx.x & 15, ty = threadIdx.x >> 4;
  int bx = blockIdx.x % 6, by = blockIdx.x / 6;
  int x0 = bx*16, y0 = by*16;

  for (int idx = threadIdx.x; idx < 46*46; idx += 256){
    int ly = idx / 46, lx = idx % 46;
    int gy = y0 - RAD + ly, gx = x0 - RAD + lx;
    float v = 0.f;
    if (gy >= 0 && gy < Hh && gx >= 0 && gx < Ww) v = qsrc[gy*Ww + gx];
    tq[ly][lx] = v;
  }
  if (threadIdx.x < TAPS) wt[threadIdx.x] = ws[OFF_WTAB + threadIdx.x];
  __syncthreads();

  for (int idx = threadIdx.x; idx < 46*16; idx += 256){
    int ly = idx >> 4, lx = idx & 15;
    float in = 0.f;
    #pragma unroll
    for (int dx=0; dx<TAPS; dx++) in = fmaf(wt[dx], tq[ly][lx+dx], in);
    tr[ly][lx] = in;
  }
  __syncthreads();

  int y = y0 + ty, x = x0 + tx, j = y*Ww + x;
  float S = 0.f;
  #pragma unroll
  for (int dy=0; dy<TAPS; dy++) S = fmaf(wt[dy], tr[ty+dy][tx], S);

  int js = ((const int*)ws)[OFF_INV + j];
  float Bv = ws[OFF_BV + js];
  ws[OFF_BV + js] = 0.f;                      // reset for next iteration's atomics
  float Cb = ws[OFF_CBI + js];
  float nb  = 1.0f/(Cb + EPSV);
  float Csp = ws[OFF_ROWW + y] * ws[OFF_ROWW + x];
  float nsp = 1.0f/(Csp + EPSV);

  float sp0 = S*nsp,  sp1 = (Csp - S)*nsp;    // q1 = 1 - q0 identity
  float bi0 = Bv*nb,  bi1 = (Cb - Bv)*nb;

  float m0 = Wsp[0]*sp0 + Wsp[1]*sp1 + Wbi[0]*bi0 + Wbi[1]*bi1;
  float m1 = Wsp[2]*sp0 + Wsp[3]*sp1 + Wbi[2]*bi0 + Wbi[3]*bi1;
  float cm0 = Cm[0]*m0 + Cm[1]*m1;
  float cm1 = Cm[2]*m0 + Cm[3]*m1;

  float o0 = logits[j]        - cm0;
  float o1 = logits[NPIX + j] - cm1;
  out[j]        = o0;
  out[NPIX + j] = o1;

  float qn = 1.0f / (1.0f + __builtin_amdgcn_exp2f((o1-o0)*LOG2E));
  qdst[j] = qn;
  ws[OFF_QS + js] = qn;
}

extern "C" void kernel_launch(void* const* d_in, const int* in_sizes, int n_in,
                              void* d_out, int out_size, void* d_ws, size_t ws_size,
                              hipStream_t stream){
  const float* image  = (const float*)d_in[0];
  const float* logits = (const float*)d_in[1];
  const float* Wsp    = (const float*)d_in[2];
  const float* Wbi    = (const float*)d_in[3];
  const float* Cm     = (const float*)d_in[4];
  float* out = (float*)d_out;
  float* ws  = (float*)d_ws;

  float* qbuf[2] = { ws + OFF_Q0, ws + OFF_Q1 };

  prepA_kernel <<<96, 256, 0, stream>>>(ws);
  prepB_kernel <<<36, 256, 0, stream>>>(image, ws);
  prepC_kernel <<<1, 256, 0, stream>>>(ws);
  prepD_kernel <<<36, 256, 0, stream>>>(image, logits, ws);
  prepE1_kernel<<<36, 256, 0, stream>>>(ws);
  prepE2_kernel<<<1, 256, 0, stream>>>(ws);

  // iteration 0: build K (fp16 blocks) + colsum + q-filter in one pass
  buildK_kernel<<<GRIDB, 256, 0, stream>>>(ws);
  combine_kernel<<<36, 256, 0, stream>>>(logits, Wsp, Wbi, Cm, ws, out,
                                         qbuf[0], qbuf[1]);
  // iterations 1..4: stream K
  for (int t=1; t<5; ++t){
    matvec_kernel<<<GRIDB, 256, 0, stream>>>(ws);
    combine_kernel<<<36, 256, 0, stream>>>(logits, Wsp, Wbi, Cm, ws, out,
                                           qbuf[t&1], qbuf[(t+1)&1]);
  }
}